// Round 6
// baseline (2604.494 us; speedup 1.0000x reference)
//
#include <hip/hip_runtime.h>

// GATv2 fused: s = a·lrelu(M@W0^T + M[rev]@W1^T + b), segment softmax over dest,
// out = segsum(alpha*M). E=800000, N=50000, D=128.
// Empirical law (R4/R5/R6): random M-row reads sustain ~3-4 G rows/s regardless of
// row bytes (256B or 512B). Row count is the currency; 1.6M random rows (M[e_i] and
// M[rev_i] per edge, bucketed per node) is the irreducible set.
// R6 (fused, 542us): ran at 2.95 G rows/s - BELOW the wall. Occupancy 44% (LDS 35.8KB
// -> 4 blocks/CU) and non-unrolled staging (~2 loads in flight/thread).
// R7: same fused dataflow, concurrency fixed: 32-row chunks + exact online softmax
// (LDS 18KB -> 8 blocks/CU), launch_bounds(256,8) (VGPR<=64; R6 measured 60),
// fully-unrolled staging (8 float4 loads in flight/thread), W frags read in-loop
// from L2-resident Wh.
// R8: identical resubmit - R7 bench died on container acquisition (infra), source
// re-audited: no divergent-barrier path, all accesses in bounds, no capture hazards.

#define SLOPE 0.2f
constexpr int E = 800000;
constexpr int N = 50000;
constexpr int D = 128;
constexpr int LDA = 264;                // halves per A row: 256 + 8 pad (bank spread)
constexpr int MAXDEG = 64;              // Poisson(16) bound; P(overflow) ~1e-13
constexpr int CHUNK = 32;               // rows staged per pass (deg<=32: 1 pass)

typedef __attribute__((ext_vector_type(8))) _Float16 f16x8;
typedef __attribute__((ext_vector_type(4))) _Float16 f16x4;
typedef __attribute__((ext_vector_type(4))) float f32x4;

// ---- K0: convert W0,W1 -> Wh[d][k] fp16, k in [0,256): [W0 row d | W1 row d]
__global__ void convert_w(const float* __restrict__ W0, const float* __restrict__ W1,
                          _Float16* __restrict__ Wh) {
    int i = blockIdx.x * blockDim.x + threadIdx.x;   // 0..32767
    if (i >= D * 256) return;
    int d = i >> 8, k = i & 255;
    float v = (k < 128) ? W0[d * 128 + k] : W1[d * 128 + (k - 128)];
    Wh[i] = (_Float16)v;                             // RNE
}

// ---- K_b: bucket edges by dest. cnt must be pre-zeroed.
__global__ void bucket_build(const int* __restrict__ dest, int* __restrict__ cnt,
                             int* __restrict__ bucket) {
    int e = blockIdx.x * blockDim.x + threadIdx.x;
    if (e >= E) return;
    int n = dest[e];
    int pos = atomicAdd(&cnt[n], 1);
    if (pos < MAXDEG) bucket[n * MAXDEG + pos] = e;
}

// ---- K1: fused per-node kernel. One 256-thread block (4 waves) per node.
// Wave w owns d-cols [w*32, w*32+32). Chunks of 32 rows, exact online softmax.
__global__ __launch_bounds__(256, 8) void fused_kernel(
    const float* __restrict__ M, const int* __restrict__ rev,
    const _Float16* __restrict__ Wh,
    const float* __restrict__ b0, const float* __restrict__ b1,
    const float* __restrict__ a_w, const float* __restrict__ a_b,
    const int* __restrict__ cnt, const int* __restrict__ bucket,
    float* __restrict__ out, float* __restrict__ alpha)
{
    __shared__ _Float16 Alds[CHUNK * LDA];    // 16896 B
    __shared__ float red[4][CHUNK];           // 512 B
    __shared__ float sL[MAXDEG];              // 256 B  raw scores (for alpha pass)
    __shared__ float pL[CHUNK];               // 128 B  exp(s - m) for current chunk
    __shared__ int   ebL[MAXDEG];             // 256 B
    __shared__ int   rvL[MAXDEG];             // 256 B
    __shared__ float sc[3];                   // 0: m_run, 1: d_run, 2: rescale f

    const int n = blockIdx.x;
    const int t = threadIdx.x;
    const int w = t >> 6;                  // wave 0..3
    const int lane = t & 63;
    const int lo = lane & 15, hi = lane >> 4;
    const int dr = w * 32;                 // this wave's d-col base
    const int cl = lane & 31;              // out col within wave's 32
    const int half = lane >> 5;            // i-parity for out accumulation
    const int col32 = t & 31;              // float4 col 0..31 (staging)
    const int rr = t >> 5;                 // staging row 0..7

    int c = cnt[n];
    c = (c > MAXDEG) ? MAXDEG : c;

    if (c == 0) {                          // empty segment: out row = 0 (uniform exit)
        if (half == 0) out[(size_t)n * D + dr + cl] = 0.f;
        return;
    }

    float bs[2], aw[2];
#pragma unroll
    for (int j = 0; j < 2; ++j) {
        int d = dr + j * 16 + lo;
        bs[j] = b0[d] + b1[d];
        aw[j] = a_w[d];
    }
    const float ab = a_b[0];

    // ---- index prefetch
    if (t < MAXDEG) {
        int e = 0, rv = 0;
        if (t < c) { e = bucket[n * MAXDEG + t]; rv = rev[e]; }
        ebL[t] = e; rvL[t] = rv;
    }
    if (t == 0) { sc[0] = -3.0e38f; sc[1] = 0.f; }
    __syncthreads();

    float u = 0.f;                         // online-rescaled Σ p_i * Mh[e_i][dr+cl]

    for (int cb = 0; cb < c; cb += CHUNK) {
        const int cc = (c - cb < CHUNK) ? (c - cb) : CHUNK;

        // ---- stage chunk: row i = [f16(M[e_i]) | f16(M[rev_i])]; 8 loads in flight
        float4 va[4], vb4[4];
#pragma unroll
        for (int q = 0; q < 4; ++q) {
            int i = q * 8 + rr;
            if (i < cc) {
                va[q]  = ((const float4*)(M + (size_t)ebL[cb + i] * D))[col32];
                vb4[q] = ((const float4*)(M + (size_t)rvL[cb + i] * D))[col32];
            }
        }
#pragma unroll
        for (int q = 0; q < 4; ++q) {
            int i = q * 8 + rr;
            if (i < cc) {
                f16x4 hv = { (_Float16)va[q].x,  (_Float16)va[q].y,
                             (_Float16)va[q].z,  (_Float16)va[q].w };
                f16x4 hu = { (_Float16)vb4[q].x, (_Float16)vb4[q].y,
                             (_Float16)vb4[q].z, (_Float16)vb4[q].w };
                *(f16x4*)(Alds + i * LDA + col32 * 4) = hv;
                *(f16x4*)(Alds + i * LDA + 128 + col32 * 4) = hu;
            }
        }
        __syncthreads();

        // ---- MFMA: 32 rows x this wave's 32 cols, K=256 (W frags from L2)
        f32x4 zero = {0.f, 0.f, 0.f, 0.f};
        f32x4 acc[2][2];
#pragma unroll
        for (int ib = 0; ib < 2; ++ib)
#pragma unroll
            for (int j = 0; j < 2; ++j) acc[ib][j] = zero;

#pragma unroll
        for (int ks = 0; ks < 8; ++ks) {
            f16x8 a0 = *(const f16x8*)(Alds + (lo)      * LDA + ks * 32 + hi * 8);
            f16x8 a1 = *(const f16x8*)(Alds + (16 + lo) * LDA + ks * 32 + hi * 8);
            f16x8 w0 = *(const f16x8*)(Wh + (dr + lo)      * 256 + ks * 32 + hi * 8);
            f16x8 w1 = *(const f16x8*)(Wh + (dr + 16 + lo) * 256 + ks * 32 + hi * 8);
            acc[0][0] = __builtin_amdgcn_mfma_f32_16x16x32_f16(a0, w0, acc[0][0], 0, 0, 0);
            acc[0][1] = __builtin_amdgcn_mfma_f32_16x16x32_f16(a0, w1, acc[0][1], 0, 0, 0);
            acc[1][0] = __builtin_amdgcn_mfma_f32_16x16x32_f16(a1, w0, acc[1][0], 0, 0, 0);
            acc[1][1] = __builtin_amdgcn_mfma_f32_16x16x32_f16(a1, w1, acc[1][1], 0, 0, 0);
        }

        // ---- epilogue: partial s over this wave's 32 cols, butterfly over lo
#pragma unroll
        for (int ib = 0; ib < 2; ++ib) {
#pragma unroll
            for (int r = 0; r < 4; ++r) {
                float v = 0.f;
#pragma unroll
                for (int j = 0; j < 2; ++j) {
                    float x = acc[ib][j][r] + bs[j];
                    x = (x > 0.f) ? x : SLOPE * x;
                    v += aw[j] * x;
                }
                v += __shfl_xor(v, 1);
                v += __shfl_xor(v, 2);
                v += __shfl_xor(v, 4);
                v += __shfl_xor(v, 8);
                if (lo == 0) red[w][ib * 16 + hi * 4 + r] = v;
            }
        }
        __syncthreads();

        // ---- online softmax update (threads 0..31 = wave-0 lanes 0..31)
        if (t < CHUNK) {
            float s = red[0][t] + red[1][t] + red[2][t] + red[3][t] + ab;
            bool valid = (t < cc);
            float sv = valid ? s : -3.0e38f;
            sL[cb + t] = sv;
            float mc = sv;
#pragma unroll
            for (int off = 1; off < 32; off <<= 1) mc = fmaxf(mc, __shfl_xor(mc, off));
            float mold = sc[0];
            float mnew = fmaxf(mold, mc);
            float p = valid ? __expf(sv - mnew) : 0.f;
            pL[t] = p;
            float ds = p;
#pragma unroll
            for (int off = 1; off < 32; off <<= 1) ds += __shfl_xor(ds, off);
            if (t == 0) {
                float f = __expf(mold - mnew);    // exp(-3e38 - m) = 0 on first chunk
                sc[2] = f;
                sc[1] = sc[1] * f + ds;
                sc[0] = mnew;
            }
        }
        __syncthreads();

        // ---- accumulate out contribution from LDS (Mh[e_i] = first 128 halves)
        float f = sc[2];
        u *= f;
        for (int i = half; i < cc; i += 2)
            u = fmaf(pL[i], (float)Alds[i * LDA + dr + cl], u);
        __syncthreads();                   // u-accum done before next chunk stages
    }

    // ---- finalize
    const float mfin = sc[0], dfin = sc[1];
    if (t < c) alpha[ebL[t]] = __expf(sL[t] - mfin) / dfin;   // 4B scatter, L2-absorbed
    u += __shfl_xor(u, 32);
    if (half == 0) out[(size_t)n * D + dr + cl] = u / dfin;
}

extern "C" void kernel_launch(void* const* d_in, const int* in_sizes, int n_in,
                              void* d_out, int out_size, void* d_ws, size_t ws_size,
                              hipStream_t stream) {
    const float* M   = (const float*)d_in[0];
    const int*   dst = (const int*)d_in[1];
    const int*   rev = (const int*)d_in[2];
    // d_in[3] = dim_size (compile-time constant N)
    const float* W0  = (const float*)d_in[4];
    const float* b0  = (const float*)d_in[5];
    const float* W1  = (const float*)d_in[6];
    const float* b1  = (const float*)d_in[7];
    const float* a_w = (const float*)d_in[8];
    const float* a_b = (const float*)d_in[9];

    float* out   = (float*)d_out;            // [N,128]
    float* alpha = out + (size_t)N * D;      // [E]

    int*       cnt    = (int*)d_ws;                      // [N]             (200000 B)
    _Float16*  Wh     = (_Float16*)(cnt + N);            // [128][256] fp16 (65536 B)
    int*       bucket = (int*)(Wh + D * 256);            // [N][MAXDEG]     (12.8 MB)

    hipMemsetAsync(cnt, 0, (size_t)N * sizeof(int), stream);

    convert_w<<<128, 256, 0, stream>>>(W0, W1, Wh);
    bucket_build<<<(E + 255) / 256, 256, 0, stream>>>(dst, cnt, bucket);
    fused_kernel<<<N, 256, 0, stream>>>(M, rev, Wh, b0, b1, a_w, a_b,
                                        cnt, bucket, out, alpha);
}